// Round 1
// baseline (1172.172 us; speedup 1.0000x reference)
//
#include <hip/hip_runtime.h>
#include <math.h>

// BiCGStab solver for implicit diffusion, 8 independent 512x512 images.
// All fields kept in ORIGINAL (untransposed) frame; output transposed at pack.

namespace {

constexpr int NIMG = 8;
constexpr int NSd  = 512;
constexpr int S    = NSd * NSd;       // 262144 elems per image-plane
constexpr int NSF  = NIMG * S;        // plane stride in floats (2,097,152)
constexpr int PADS = 514;
constexpr float EPSF = 1e-9f;
#define THRESH (1e-9f * 262144.0f)
constexpr float RX_  = 50.0f;   // TAU/(2*HX)
constexpr float RY_  = 50.0f;
constexpr float RXX_ = 100.0f;  // TAU/HX^2
constexpr float RYY_ = 100.0f;

// plane indices within ws
enum { P_BOO=0, P_BXM, P_BXP, P_BYM, P_BYP, P_X, P_R, P_R0, P_P, P_V, P_S, P_T, NPLANES };

// aux area (floats), offset from ws + NPLANES*NSF
constexpr int A_MEAN = 0;      // 8 floats
constexpr int A_SC   = 8;      // 8*16 floats
constexpr int A_FL   = 136;    // 8*8 ints (aliased)
constexpr int A_PA   = 200;    // 512 floats (block partials buf A)
constexpr int A_PB   = 712;    // 512 floats (block partials buf B)

enum { SC_RABS=0, SC_R0ABS, SC_RR0, SC_SIGMA, SC_VABS, SC_ALPHA, SC_OMEGA, SC_BETA, SC_SNORM };
enum { F_CONV=0, F_RES1, F_NRES, F_C3, F_C4, F_K };

__device__ __forceinline__ int cl(int i){ return i < 0 ? 0 : (i > NSd-1 ? NSd-1 : i); }

// A(z)[Y,X] with symmetric (clamped) interior padding, reference summation order:
// boo*zc + bmo*z[x-1] + bom*z[y-1] + bop*z[y+1] + bpo*z[x+1]
__device__ __forceinline__ float applyA(const float* __restrict__ ws, int zp, int bS, int Y, int X){
  const float* z = ws + zp*NSF;
  int row = bS + (Y<<9);
  float zc  = z[row + X];
  float zxm = z[row + cl(X-1)];
  float zxp = z[row + cl(X+1)];
  float zym = z[bS + (cl(Y-1)<<9) + X];
  float zyp = z[bS + (cl(Y+1)<<9) + X];
  int o = row + X;
  return ws[P_BOO*NSF+o]*zc + ws[P_BXM*NSF+o]*zxm + ws[P_BYM*NSF+o]*zym
       + ws[P_BYP*NSF+o]*zyp + ws[P_BXP*NSF+o]*zxp;
}

__device__ __forceinline__ void store_red2(float a, float b, float* pa, float* pb){
  for (int o = 32; o; o >>= 1){ a += __shfl_xor(a, o); b += __shfl_xor(b, o); }
  __shared__ float sa[4], sb[4];
  int w = threadIdx.x >> 6;
  if ((threadIdx.x & 63) == 0){ sa[w] = a; sb[w] = b; }
  __syncthreads();
  if (threadIdx.x == 0){
    *pa = sa[0]+sa[1]+sa[2]+sa[3];
    *pb = sb[0]+sb[1]+sb[2]+sb[3];
  }
}

__device__ __forceinline__ void store_red1(float a, float* pa, float scale){
  for (int o = 32; o; o >>= 1) a += __shfl_xor(a, o);
  __shared__ float sa[4];
  int w = threadIdx.x >> 6;
  if ((threadIdx.x & 63) == 0) sa[w] = a;
  __syncthreads();
  if (threadIdx.x == 0) *pa = (sa[0]+sa[1]+sa[2]+sa[3]) * scale;
}

// ---------------- setup kernels ----------------

__global__ void kmean(const float* __restrict__ V, float* __restrict__ ws){
  int b = blockIdx.x;
  const float* v = V + b*S;
  float s = 0.f;
  for (int e = threadIdx.x; e < S; e += 256) s += v[e];
  float* aux = ws + NPLANES*NSF;
  store_red1(s, &aux[A_MEAN + b], 1.0f/262144.0f);
}

__global__ void kcoef(const float* __restrict__ V, const float* __restrict__ M1,
                      const float* __restrict__ M2, float* __restrict__ ws){
  int idx = blockIdx.x*256 + threadIdx.x;   // global [b][Y][X] flat, 8*S threads
  int rem = idx & (S-1);
  int b   = idx >> 18;
  int Y = rem >> 9, X = rem & (NSd-1);
  const float* v  = V  + b*S;
  const float* m1 = M1 + b*S;
  const float* m2 = M2 + b*S;
  float a   = v[rem];
  float vxp = v[(Y<<9) + cl(X+1)];
  float vxm = v[(Y<<9) + cl(X-1)];
  float vyp = v[(cl(Y+1)<<9) + X];
  float vym = v[(cl(Y-1)<<9) + X];
  float m1c = m1[rem];
  float m1m = m1[(Y<<9) + cl(X-1)];
  float m2c = m2[rem];
  float m2m = m2[(cl(Y-1)<<9) + X];
  // D1f[y,x], D1f[y,x-1], D2f[y,x], D2f[y-1,x]  (y=Y+1, x=X+1 padded coords)
  float d1x  = ((vxp - a) / (0.5f*(vxp + a))) * m1c;
  float d1xm = ((a - vxm) / (0.5f*(a + vxm))) * m1m;
  float d2y  = ((vyp - a) / (0.5f*(vyp + a))) * m2c;
  float d2ym = ((a - vym) / (0.5f*(a + vym))) * m2m;
  ws[P_BOO*NSF + idx] = 1.0f + 2.0f*(RXX_+RYY_) - RX_*(d1xm - d1x) - RY_*(d2ym - d2y);
  ws[P_BXP*NSF + idx] = -RXX_ + RX_*d1x;
  ws[P_BXM*NSF + idx] = -RXX_ - RX_*d1xm;
  ws[P_BYP*NSF + idx] = -RYY_ + RY_*d2y;
  ws[P_BYM*NSF + idx] = -RYY_ - RY_*d2ym;
}

__global__ void kinit(float* __restrict__ ws){
  float* aux = ws + NPLANES*NSF;
  int b = blockIdx.x >> 6, blk = blockIdx.x & 63;
  int bS = b*S, row0 = blk*8;
  float c = aux[A_MEAN + b];
  float* x  = ws + P_X*NSF;
  float* r  = ws + P_R*NSF;
  float* r0 = ws + P_R0*NSF;
  float* p  = ws + P_P*NSF;
  float s1 = 0.f;
  for (int e = threadIdx.x; e < 4096; e += 256){
    int Y = row0 + (e>>9), X = e & (NSd-1);
    int o = bS + (Y<<9) + X;
    float val = ws[P_BOO*NSF+o]*c + ws[P_BXM*NSF+o]*c + ws[P_BYM*NSF+o]*c
              + ws[P_BYP*NSF+o]*c + ws[P_BXP*NSF+o]*c;
    float pn = c - val;        // p0 = b - A(x0), x0 == const c
    x[o] = c; r[o] = pn; r0[o] = pn; p[o] = pn;
    s1 += pn*pn;
  }
  store_red1(s1, &aux[A_PA + blockIdx.x], 1.0f);
}

__global__ void kscal0(float* __restrict__ ws, const int* __restrict__ km){
  float* aux = ws + NPLANES*NSF;
  float* sc = aux + A_SC;
  int* fl = (int*)(aux + A_FL);
  int b = threadIdx.x >> 6, lane = threadIdx.x & 63;
  float a = aux[A_PA + b*64 + lane];
  for (int o = 32; o; o >>= 1) a += __shfl_xor(a, o);
  if (lane == 0){
    int kmax = *km;
    float ra = sqrtf(a);
    sc[b*16+SC_RABS] = ra; sc[b*16+SC_R0ABS] = ra; sc[b*16+SC_RR0] = a;
    sc[b*16+SC_SIGMA]=0.f; sc[b*16+SC_VABS]=0.f; sc[b*16+SC_ALPHA]=0.f;
    sc[b*16+SC_OMEGA]=0.f; sc[b*16+SC_BETA]=0.f; sc[b*16+SC_SNORM]=0.f;
    fl[b*8+F_K] = 0;
    fl[b*8+F_CONV] = (0 < kmax) && (ra > THRESH);
    fl[b*8+F_RES1]=0; fl[b*8+F_NRES]=0; fl[b*8+F_C3]=0; fl[b*8+F_C4]=0;
  }
}

// ---------------- per-iteration kernels ----------------

// v = A(p); partials: pa=sum(v*r0), pb=sum(v*v)      [conv]
__global__ void kv(float* __restrict__ ws){
  float* aux = ws + NPLANES*NSF;
  int* fl = (int*)(aux + A_FL);
  int b = blockIdx.x >> 6;
  if (!fl[b*8+F_CONV]) return;
  int blk = blockIdx.x & 63, bS = b*S, row0 = blk*8;
  const float* r0 = ws + P_R0*NSF;
  float* v = ws + P_V*NSF;
  float s1 = 0.f, s2 = 0.f;
  for (int e = threadIdx.x; e < 4096; e += 256){
    int Y = row0 + (e>>9), X = e & (NSd-1);
    float val = applyA(ws, P_P, bS, Y, X);
    int o = bS + (Y<<9) + X;
    v[o] = val;
    s1 += val * r0[o];
    s2 += val * val;
  }
  store_red2(s1, s2, &aux[A_PA + blockIdx.x], &aux[A_PB + blockIdx.x]);
}

// sigma, v_abs, res -> res1/nres flags, alpha
__global__ void kscalA(float* __restrict__ ws){
  float* aux = ws + NPLANES*NSF;
  float* sc = aux + A_SC;
  int* fl = (int*)(aux + A_FL);
  int b = threadIdx.x >> 6, lane = threadIdx.x & 63;
  int conv = fl[b*8+F_CONV];
  float a1 = aux[A_PA + b*64 + lane];
  float a2 = aux[A_PB + b*64 + lane];
  for (int o = 32; o; o >>= 1){ a1 += __shfl_xor(a1, o); a2 += __shfl_xor(a2, o); }
  if (lane == 0){
    int res1 = 0, nres = 0;
    if (conv){
      float sigma = a1, vabs = sqrtf(a2);
      sc[b*16+SC_SIGMA] = sigma; sc[b*16+SC_VABS] = vabs;
      int res = (sigma <= EPSF * vabs * sc[b*16+SC_R0ABS]);
      res1 = res; nres = !res;
      if (nres) sc[b*16+SC_ALPHA] = sc[b*16+SC_RR0] / sigma;
    }
    fl[b*8+F_RES1] = res1; fl[b*8+F_NRES] = nres;
  }
}

// res1: p=r=r0 = b - A(x), pa=sum(pn^2)   nres: s = r - alpha*v, pb=sum(s^2)
__global__ void krs(float* __restrict__ ws){
  float* aux = ws + NPLANES*NSF;
  float* sc = aux + A_SC;
  int* fl = (int*)(aux + A_FL);
  int b = blockIdx.x >> 6;
  int res1 = fl[b*8+F_RES1], nres = fl[b*8+F_NRES];
  if (!res1 && !nres) return;
  int blk = blockIdx.x & 63, bS = b*S, row0 = blk*8;
  if (res1){
    float c = aux[A_MEAN + b];
    float* p  = ws + P_P*NSF;
    float* r  = ws + P_R*NSF;
    float* r0 = ws + P_R0*NSF;
    float s1 = 0.f;
    for (int e = threadIdx.x; e < 4096; e += 256){
      int Y = row0 + (e>>9), X = e & (NSd-1);
      float pn = c - applyA(ws, P_X, bS, Y, X);
      int o = bS + (Y<<9) + X;
      p[o] = pn; r[o] = pn; r0[o] = pn;
      s1 += pn*pn;
    }
    store_red1(s1, &aux[A_PA + blockIdx.x], 1.0f);
  } else {
    float alpha = sc[b*16+SC_ALPHA];
    const float* r = ws + P_R*NSF;
    const float* v = ws + P_V*NSF;
    float* s = ws + P_S*NSF;
    float s2 = 0.f;
    for (int e = threadIdx.x; e < 4096; e += 256){
      int Y = row0 + (e>>9), X = e & (NSd-1);
      int o = bS + (Y<<9) + X;
      float sv = r[o] - alpha*v[o];
      s[o] = sv;
      s2 += sv*sv;
    }
    store_red1(s2, &aux[A_PB + blockIdx.x], 1.0f);
  }
}

// restart scalar finish; snorm -> c3/c4 flags
__global__ void kscalB(float* __restrict__ ws){
  float* aux = ws + NPLANES*NSF;
  float* sc = aux + A_SC;
  int* fl = (int*)(aux + A_FL);
  int b = threadIdx.x >> 6, lane = threadIdx.x & 63;
  int res1 = fl[b*8+F_RES1], nres = fl[b*8+F_NRES];
  float a1 = aux[A_PA + b*64 + lane];
  float a2 = aux[A_PB + b*64 + lane];
  for (int o = 32; o; o >>= 1){ a1 += __shfl_xor(a1, o); a2 += __shfl_xor(a2, o); }
  if (lane == 0){
    int c3 = 0, c4 = 0;
    if (res1){
      float ra = sqrtf(a1);
      sc[b*16+SC_R0ABS] = ra; sc[b*16+SC_RABS] = ra; sc[b*16+SC_RR0] = a1;
      fl[b*8+F_K] += 1;
    }
    if (nres){
      float sn = sqrtf(a2);
      sc[b*16+SC_SNORM] = sn;
      c3 = (sn <= THRESH);
      c4 = !c3;
    }
    fl[b*8+F_C3] = c3; fl[b*8+F_C4] = c4;
  }
}

// t = A(s); pa=sum(t*s), pb=sum(t*t)     [c4]
__global__ void kt(float* __restrict__ ws){
  float* aux = ws + NPLANES*NSF;
  int* fl = (int*)(aux + A_FL);
  int b = blockIdx.x >> 6;
  if (!fl[b*8+F_C4]) return;
  int blk = blockIdx.x & 63, bS = b*S, row0 = blk*8;
  const float* s = ws + P_S*NSF;
  float* t = ws + P_T*NSF;
  float s1 = 0.f, s2 = 0.f;
  for (int e = threadIdx.x; e < 4096; e += 256){
    int Y = row0 + (e>>9), X = e & (NSd-1);
    float val = applyA(ws, P_S, bS, Y, X);
    int o = bS + (Y<<9) + X;
    t[o] = val;
    s1 += val * s[o];
    s2 += val * val;
  }
  store_red2(s1, s2, &aux[A_PA + blockIdx.x], &aux[A_PB + blockIdx.x]);
}

// omega = <t,s>/<t,t>   [c4]
__global__ void kscalC(float* __restrict__ ws){
  float* aux = ws + NPLANES*NSF;
  float* sc = aux + A_SC;
  int* fl = (int*)(aux + A_FL);
  int b = threadIdx.x >> 6, lane = threadIdx.x & 63;
  int c4 = fl[b*8+F_C4];
  float a1 = aux[A_PA + b*64 + lane];
  float a2 = aux[A_PB + b*64 + lane];
  for (int o = 32; o; o >>= 1){ a1 += __shfl_xor(a1, o); a2 += __shfl_xor(a2, o); }
  if (lane == 0 && c4) sc[b*16+SC_OMEGA] = a1 / a2;
}

// c3: x += alpha*p; r = s.   c4: x += alpha*p + omega*s; r = s - omega*t; pa=<r,r0>, pb=<r,r>
__global__ void kupd(float* __restrict__ ws){
  float* aux = ws + NPLANES*NSF;
  float* sc = aux + A_SC;
  int* fl = (int*)(aux + A_FL);
  int b = blockIdx.x >> 6;
  int c3 = fl[b*8+F_C3], c4 = fl[b*8+F_C4];
  if (!c3 && !c4) return;
  int blk = blockIdx.x & 63, bS = b*S, row0 = blk*8;
  float alpha = sc[b*16+SC_ALPHA];
  float* x = ws + P_X*NSF;
  float* r = ws + P_R*NSF;
  const float* p = ws + P_P*NSF;
  const float* s = ws + P_S*NSF;
  if (c3){
    for (int e = threadIdx.x; e < 4096; e += 256){
      int Y = row0 + (e>>9), X = e & (NSd-1);
      int o = bS + (Y<<9) + X;
      x[o] = x[o] + alpha*p[o];
      r[o] = s[o];
    }
  } else {
    float omega = sc[b*16+SC_OMEGA];
    const float* t  = ws + P_T*NSF;
    const float* r0 = ws + P_R0*NSF;
    float s1 = 0.f, s2 = 0.f;
    for (int e = threadIdx.x; e < 4096; e += 256){
      int Y = row0 + (e>>9), X = e & (NSd-1);
      int o = bS + (Y<<9) + X;
      x[o] = x[o] + alpha*p[o] + omega*s[o];
      float rn = s[o] - omega*t[o];
      r[o] = rn;
      s1 += rn * r0[o];
      s2 += rn * rn;
    }
    store_red2(s1, s2, &aux[A_PA + blockIdx.x], &aux[A_PB + blockIdx.x]);
  }
}

// beta, rr0, r_abs, k; next-iter conv for ALL images
__global__ void kscalD(float* __restrict__ ws, const int* __restrict__ km){
  float* aux = ws + NPLANES*NSF;
  float* sc = aux + A_SC;
  int* fl = (int*)(aux + A_FL);
  int b = threadIdx.x >> 6, lane = threadIdx.x & 63;
  int c3 = fl[b*8+F_C3], c4 = fl[b*8+F_C4];
  float a1 = aux[A_PA + b*64 + lane];
  float a2 = aux[A_PB + b*64 + lane];
  for (int o = 32; o; o >>= 1){ a1 += __shfl_xor(a1, o); a2 += __shfl_xor(a2, o); }
  if (lane == 0){
    if (c4){
      float beta = sc[b*16+SC_ALPHA] / sc[b*16+SC_OMEGA] * (a1 / sc[b*16+SC_RR0]);
      sc[b*16+SC_BETA] = beta;
      sc[b*16+SC_RR0]  = a1;
      sc[b*16+SC_RABS] = sqrtf(a2);
      fl[b*8+F_K] += 1;
    }
    if (c3){
      sc[b*16+SC_RABS] = sc[b*16+SC_SNORM];
      fl[b*8+F_K] += 1;
    }
    int kk = fl[b*8+F_K];
    fl[b*8+F_CONV] = (kk < *km) && (sc[b*16+SC_RABS] > THRESH);
  }
}

// p = r + beta*(p - omega*v)     [c4]
__global__ void kp(float* __restrict__ ws){
  float* aux = ws + NPLANES*NSF;
  float* sc = aux + A_SC;
  int* fl = (int*)(aux + A_FL);
  int b = blockIdx.x >> 6;
  if (!fl[b*8+F_C4]) return;
  int blk = blockIdx.x & 63, bS = b*S, row0 = blk*8;
  float beta  = sc[b*16+SC_BETA];
  float omega = sc[b*16+SC_OMEGA];
  float* p = ws + P_P*NSF;
  const float* r = ws + P_R*NSF;
  const float* v = ws + P_V*NSF;
  for (int e = threadIdx.x; e < 4096; e += 256){
    int Y = row0 + (e>>9), X = e & (NSd-1);
    int o = bS + (Y<<9) + X;
    p[o] = r[o] + beta*(p[o] - omega*v[o]);
  }
}

// out[b][i][j] (514x514 transposed-padded): border=mean, interior=x[j-1][i-1]
__global__ void kpack(const float* __restrict__ ws, float* __restrict__ out){
  int b = blockIdx.y;
  int idx = blockIdx.x*256 + threadIdx.x;
  if (idx >= PADS*PADS) return;
  int i = idx / PADS, j = idx % PADS;
  const float* aux = ws + NPLANES*NSF;
  float val;
  if (i == 0 || i == PADS-1 || j == 0 || j == PADS-1) val = aux[A_MEAN + b];
  else val = ws[P_X*NSF + b*S + ((j-1)<<9) + (i-1)];
  out[b*(PADS*PADS) + idx] = val;
}

} // namespace

extern "C" void kernel_launch(void* const* d_in, const int* in_sizes, int n_in,
                              void* d_out, int out_size, void* d_ws, size_t ws_size,
                              hipStream_t stream) {
  const float* V  = (const float*)d_in[0];
  const float* M1 = (const float*)d_in[1];
  const float* M2 = (const float*)d_in[2];
  const int*   km = (const int*)d_in[3];
  float* ws  = (float*)d_ws;
  float* out = (float*)d_out;

  size_t need = ((size_t)NPLANES * NSF + 2048) * sizeof(float);
  if (ws_size < need) return;  // workspace too small; fail loudly via wrong output

  kmean <<<NIMG, 256, 0, stream>>>(V, ws);
  kcoef <<<NIMG*S/256, 256, 0, stream>>>(V, M1, M2, ws);
  kinit <<<512, 256, 0, stream>>>(ws);
  kscal0<<<1, 512, 0, stream>>>(ws, km);

  for (int it = 0; it < 16; ++it){
    kv    <<<512, 256, 0, stream>>>(ws);
    kscalA<<<1, 512, 0, stream>>>(ws);
    krs   <<<512, 256, 0, stream>>>(ws);
    kscalB<<<1, 512, 0, stream>>>(ws);
    kt    <<<512, 256, 0, stream>>>(ws);
    kscalC<<<1, 512, 0, stream>>>(ws);
    kupd  <<<512, 256, 0, stream>>>(ws);
    kscalD<<<1, 512, 0, stream>>>(ws, km);
    kp    <<<512, 256, 0, stream>>>(ws);
  }

  kpack<<<dim3((PADS*PADS + 255)/256, NIMG), 256, 0, stream>>>(ws, out);
}